// Round 9
// baseline (116.665 us; speedup 1.0000x reference)
//
#include <hip/hip_runtime.h>
#include <hip/hip_bf16.h>

// Segment mean: N values, sorted segment ids, NC segments.
// Persistent blocks + register double-buffered chunk pipeline: chunk t+1's
// loads are issued before chunk t is processed, so the VMEM pipe never
// drains on a waitcnt. Flat per-run atomics (proven not the wall in r5/r7).

#define VPT 16
#define BLOCK 256
#define CHUNK (VPT * BLOCK)   // 4096 elements per block-chunk
#define GRID 2048             // persistent; nchunks/GRID = 2 for N=16.7M

typedef float fx4 __attribute__((ext_vector_type(4)));   // clang vector: OK for nontemporal
typedef int   ix4 __attribute__((ext_vector_type(4)));

__global__ __launch_bounds__(BLOCK)
void seg_sum_kernel(const float* __restrict__ x,
                    const void* __restrict__ seg,
                    float* __restrict__ gsums,
                    float* __restrict__ gcnts,
                    int n, int nchunks) {
    const int* s32 = (const int*)seg;
    const long long* s64 = (const long long*)seg;
    // dtype sniff: int64 storage => int32 word [n-1] is a high word (0, ids < 2^18);
    // int32 storage => largest sorted id (nonzero).
    const bool is64 = (s32[n - 1] == 0);

    const int tid = threadIdx.x;

    float vA[VPT]; int iA[VPT]; int nvA = 0;
    float vB[VPT]; int iB[VPT]; int nvB = 0;

    // LOADBUF: issue vector loads for chunk g into (vv, ii, nv).
    // x via nontemporal (zero reuse; keep ids' L3 residency untouched).
#define LOADBUF(vv, ii, nv, g)                                                 \
    {                                                                          \
        const long long base_ = (long long)(g) * CHUNK + (long long)tid * VPT; \
        nv = 0;                                                                \
        if (base_ < n) {                                                       \
            long long rem_ = (long long)n - base_;                             \
            nv = (rem_ >= VPT) ? VPT : (int)rem_;                              \
        }                                                                      \
        if (nv == VPT) {                                                       \
            const fx4* xv_ = (const fx4*)(x + base_);                          \
            _Pragma("unroll")                                                  \
            for (int k = 0; k < 4; ++k) {                                      \
                fx4 a_ = __builtin_nontemporal_load(xv_ + k);                  \
                vv[4 * k]     = a_.x;                                          \
                vv[4 * k + 1] = a_.y;                                          \
                vv[4 * k + 2] = a_.z;                                          \
                vv[4 * k + 3] = a_.w;                                          \
            }                                                                  \
            if (is64) {                                                        \
                const ix4* iv_ = (const ix4*)(s64 + base_);                    \
                _Pragma("unroll")                                              \
                for (int k = 0; k < 8; ++k) {                                  \
                    ix4 t_ = iv_[k];                                           \
                    ii[2 * k]     = t_.x;                                      \
                    ii[2 * k + 1] = t_.z;                                      \
                }                                                              \
            } else {                                                           \
                const ix4* iv_ = (const ix4*)(s32 + base_);                    \
                _Pragma("unroll")                                              \
                for (int k = 0; k < 4; ++k) {                                  \
                    ix4 t_ = iv_[k];                                           \
                    ii[4 * k]     = t_.x;                                      \
                    ii[4 * k + 1] = t_.y;                                      \
                    ii[4 * k + 2] = t_.z;                                      \
                    ii[4 * k + 3] = t_.w;                                      \
                }                                                              \
            }                                                                  \
        } else {                                                               \
            _Pragma("unroll")                                                  \
            for (int k = 0; k < VPT; ++k) {                                    \
                if (k < nv) {                                                  \
                    ii[k] = is64 ? (int)s64[base_ + k] : s32[base_ + k];       \
                    vv[k] = x[base_ + k];                                      \
                } else {                                                       \
                    ii[k] = -1;                                                \
                    vv[k] = 0.0f;                                              \
                }                                                              \
            }                                                                  \
        }                                                                      \
    }

    // PROCESS: sequential run-merge; flush each closed run (and trailer)
    // with a pair of global atomics.
#define PROCESS(vv, ii, nv)                                                    \
    if (nv > 0) {                                                              \
        int   cur_ = ii[0];                                                    \
        float s_   = vv[0];                                                    \
        float c_   = 1.0f;                                                     \
        _Pragma("unroll")                                                      \
        for (int k = 1; k < VPT; ++k) {                                        \
            if (k < nv) {                                                      \
                if (ii[k] == cur_) {                                           \
                    s_ += vv[k];                                               \
                    c_ += 1.0f;                                                \
                } else {                                                       \
                    atomicAdd(&gsums[cur_], s_);                               \
                    atomicAdd(&gcnts[cur_], c_);                               \
                    cur_ = ii[k];                                              \
                    s_ = vv[k];                                                \
                    c_ = 1.0f;                                                 \
                }                                                              \
            }                                                                  \
        }                                                                      \
        atomicAdd(&gsums[cur_], s_);                                           \
        atomicAdd(&gcnts[cur_], c_);                                           \
    }

    int g = blockIdx.x;
    if (g >= nchunks) return;

    LOADBUF(vA, iA, nvA, g)
    while (true) {
        // A in flight/ready. Prefetch B, then process A.
        {
            int gn = g + GRID;
            if (gn < nchunks) LOADBUF(vB, iB, nvB, gn)
        }
        PROCESS(vA, iA, nvA)
        g += GRID;
        if (g >= nchunks) break;

        // B ready. Prefetch A, then process B.
        {
            int gn = g + GRID;
            if (gn < nchunks) LOADBUF(vA, iA, nvA, gn)
        }
        PROCESS(vB, iB, nvB)
        g += GRID;
        if (g >= nchunks) break;
    }
#undef LOADBUF
#undef PROCESS
}

__global__ void finalize_kernel(float* __restrict__ out,
                                const float* __restrict__ gsums,
                                const float* __restrict__ gcnts,
                                int nc) {
    int c = blockIdx.x * blockDim.x + threadIdx.x;
    if (c < nc) {
        float cv = gcnts[c];
        out[c] = (cv > 0.0f) ? (gsums[c] / cv) : 0.0f;
    }
}

extern "C" void kernel_launch(void* const* d_in, const int* in_sizes, int n_in,
                              void* d_out, int out_size, void* d_ws, size_t ws_size,
                              hipStream_t stream) {
    const float* x = (const float*)d_in[0];
    const void* seg = d_in[1];
    const int n = in_sizes[0];     // 16777216
    const int nc = out_size;       // 262144

    float* gsums = (float*)d_ws;          // [nc]
    float* gcnts = (float*)d_ws + nc;     // [nc]
    float* out   = (float*)d_out;

    // Re-zero accumulators every call (harness does not re-poison between
    // graph replays).
    (void)hipMemsetAsync(gsums, 0, (size_t)2 * nc * sizeof(float), stream);

    const int nchunks = (int)(((long long)n + CHUNK - 1) / CHUNK);  // 4096
    seg_sum_kernel<<<GRID, BLOCK, 0, stream>>>(x, seg, gsums, gcnts, n, nchunks);

    const int fgrid = (nc + BLOCK - 1) / BLOCK;
    finalize_kernel<<<fgrid, BLOCK, 0, stream>>>(out, gsums, gcnts, nc);
}

// Round 10
// 41.296 us; speedup vs baseline: 2.8251x; 2.8251x over previous
//
#include <hip/hip_runtime.h>
#include <hip/hip_bf16.h>

// Segment mean: N values, sorted segment ids, NC segments.
// r10: ids (the 2/3-of-traffic stream) staged via global_load_lds DMA into
// LDS (bypasses the ~7 B/cy/CU L1-return path that pinned r3/r5/r7 at
// ~4.4 TB/s); x stays on direct VGPR loads (parallel path). Merge + wave
// segmented scan + atomics identical to r5 (proven correct & fast enough).

#define BLOCK 256
#define VPT 8
#define CHUNK (BLOCK * VPT)    // 2048 elements per block
#define NWAVES (BLOCK / 64)    // 4

typedef float fx4 __attribute__((ext_vector_type(4)));
typedef const __attribute__((address_space(1))) unsigned int gas_u32;
typedef __attribute__((address_space(3))) unsigned int las_u32;

__global__ __launch_bounds__(BLOCK)
void seg_sum_kernel(const float* __restrict__ x,
                    const void* __restrict__ seg,
                    float* __restrict__ gsums,
                    float* __restrict__ gcnts,
                    int n) {
    __shared__ int lid[CHUNK * 2];   // raw id words: int64 -> 16 KB, int32 -> 8 KB used

    const int* s32 = (const int*)seg;
    // dtype sniff: int64 storage => int32 word [n-1] is a high word (0, ids < 2^18);
    // int32 storage => largest sorted id (nonzero).
    const bool is64 = (s32[n - 1] == 0);

    const int tid = threadIdx.x;
    const int wave = tid >> 6;
    const int lane = tid & 63;
    const long long bbase = (long long)blockIdx.x * CHUNK;

    // ---- stage raw id bytes via global_load_lds (linear LDS dest:
    //      wave-uniform base + lane*16; per-lane global source). ----
    {
        const char* segb = (const char*)seg;
        const int eb = is64 ? 8 : 4;                       // bytes per id
        const long long gbytes_lo  = bbase * eb;
        const long long gbytes_end = (long long)n * eb;    // region extent
        const int ops = (CHUNK / 1024) * eb * (1024 / 16) / 64;  // = CHUNK*eb/1024: 16 or 8
        for (int op = wave; op < ops; op += NWAVES) {
            long long goff = gbytes_lo + (long long)op * 1024 + (long long)lane * 16;
            long long gmax = gbytes_end - 16;
            if (goff > gmax) goff = gmax;                  // whole-16B clamp (dup ok)
            if (goff < 0) goff = 0;
            __builtin_amdgcn_global_load_lds(
                (gas_u32*)(segb + goff),
                (las_u32*)((char*)lid + (size_t)op * 1024),
                16, 0, 0);
        }
    }

    // ---- x loads: direct to VGPR (independent of LDS; issues under DMA). ----
    float vals[VPT];
    const long long base = bbase + (long long)tid * VPT;
    int nv = 0;
    if (base < n) {
        long long rem = (long long)n - base;
        nv = (rem >= VPT) ? VPT : (int)rem;
    }
    if (nv == VPT) {
        const fx4* xv = (const fx4*)(x + base);
        fx4 a = xv[0], b = xv[1];
        vals[0] = a.x; vals[1] = a.y; vals[2] = a.z; vals[3] = a.w;
        vals[4] = b.x; vals[5] = b.y; vals[6] = b.z; vals[7] = b.w;
    } else {
        #pragma unroll
        for (int k = 0; k < VPT; ++k)
            vals[k] = (k < nv) ? x[base + k] : 0.0f;
    }

    // ---- tail-block repair: clamped DMA may have mis-filled positions near n.
    //      Block-uniform branch; only the last (partial) block pays it. ----
    if (bbase + CHUNK > (long long)n) {
        __syncthreads();   // drain DMA before overwriting
        for (long long p = bbase + tid; p < bbase + CHUNK; p += BLOCK) {
            int li = (int)(p - bbase);
            if (p < (long long)n) {
                if (is64) lid[li * 2] = (int)((const long long*)seg)[p];
                else      lid[li]     = s32[p];
            } else {
                if (is64) lid[li * 2] = -1;
                else      lid[li]     = -1;
            }
        }
    }
    __syncthreads();       // DMA (and any repair) visible

    // ---- id readback from LDS ----
    int ids_[VPT];
    #pragma unroll
    for (int k = 0; k < VPT; ++k) {
        int li = tid * VPT + k;
        ids_[k] = is64 ? lid[li * 2] : lid[li];
        if (k >= nv) ids_[k] = -1;
    }

    // ---- r5-proven: sequential run-merge; flush closed runs. ----
    if (nv > 0) {
        int   cur = ids_[0];
        float s   = vals[0];
        float c   = 1.0f;
        #pragma unroll
        for (int k = 1; k < VPT; ++k) {
            if (k < nv) {
                if (ids_[k] == cur) {
                    s += vals[k];
                    c += 1.0f;
                } else {
                    atomicAdd(&gsums[cur], s);
                    atomicAdd(&gcnts[cur], c);
                    cur = ids_[k];
                    s = vals[k];
                    c = 1.0f;
                }
            }
        }

        // Wave segmented scan over trailing runs (sortedness makes the
        // equality guard exact).
        int lid_ = cur;
        #pragma unroll
        for (int off = 1; off < 64; off <<= 1) {
            float os = __shfl_up(s, off);
            float oc = __shfl_up(c, off);
            int  oid = __shfl_up(lid_, off);
            if (lane >= off && oid == lid_) {
                s += os;
                c += oc;
            }
        }
        int nid = __shfl_down(lid_, 1);
        bool emit = (lane == 63) || (nid != lid_);
        if (emit) {
            atomicAdd(&gsums[lid_], s);
            atomicAdd(&gcnts[lid_], c);
        }
    } else {
        // inactive threads still participate in shuffles deterministically
        int lid_ = -1;
        float s = 0.0f, c = 0.0f;
        #pragma unroll
        for (int off = 1; off < 64; off <<= 1) {
            float os = __shfl_up(s, off);
            float oc = __shfl_up(c, off);
            int  oid = __shfl_up(lid_, off);
            if (lane >= off && oid == lid_) {
                s += os;
                c += oc;
            }
        }
        (void)__shfl_down(lid_, 1);
    }
}

__global__ void finalize_kernel(float* __restrict__ out,
                                const float* __restrict__ gsums,
                                const float* __restrict__ gcnts,
                                int nc) {
    int c = blockIdx.x * blockDim.x + threadIdx.x;
    if (c < nc) {
        float cv = gcnts[c];
        out[c] = (cv > 0.0f) ? (gsums[c] / cv) : 0.0f;
    }
}

extern "C" void kernel_launch(void* const* d_in, const int* in_sizes, int n_in,
                              void* d_out, int out_size, void* d_ws, size_t ws_size,
                              hipStream_t stream) {
    const float* x = (const float*)d_in[0];
    const void* seg = d_in[1];
    const int n = in_sizes[0];     // 16777216
    const int nc = out_size;       // 262144

    float* gsums = (float*)d_ws;          // [nc]
    float* gcnts = (float*)d_ws + nc;     // [nc]
    float* out   = (float*)d_out;

    // Re-zero accumulators every call (harness does not re-poison between
    // graph replays).
    (void)hipMemsetAsync(gsums, 0, (size_t)2 * nc * sizeof(float), stream);

    const int grid = (int)(((long long)n + CHUNK - 1) / CHUNK);   // 8192
    seg_sum_kernel<<<grid, BLOCK, 0, stream>>>(x, seg, gsums, gcnts, n);

    const int fgrid = (nc + BLOCK - 1) / BLOCK;
    finalize_kernel<<<fgrid, BLOCK, 0, stream>>>(out, gsums, gcnts, nc);
}